// Round 12
// baseline (400.857 us; speedup 1.0000x reference)
//
#include <hip/hip_runtime.h>
#include <cstdint>
#include <cstddef>

#define NN 100000
#define NE 1600000
#define F  128
#define NPAD 100352          // 98 * 1024
#define NBUCK 782            // ceil(NN / 128) buckets of 128 nodes
#define BCAPG 2560           // padded region capacity per bucket (mean 2046, +11 sd)
#define CHUNK 4167           // ceil(NE / 384) fill blocks
#define SCALEB 512           // scale-role blocks in sortscale kernel

typedef __attribute__((ext_vector_type(8))) short bf16x8;
typedef __attribute__((ext_vector_type(4))) float f32x4;

// bf16 helpers (RNE)
__device__ __forceinline__ unsigned short f2bf(float f) {
    unsigned u = __float_as_uint(f);
    unsigned r = (u + 0x7fffu + ((u >> 16) & 1u)) >> 16;
    return (unsigned short)r;
}
__device__ __forceinline__ void acc_bf4(const uint2 v, float* acc) {
    acc[0] += __uint_as_float(v.x << 16);
    acc[1] += __uint_as_float(v.x & 0xffff0000u);
    acc[2] += __uint_as_float(v.y << 16);
    acc[3] += __uint_as_float(v.y & 0xffff0000u);
}
__device__ __forceinline__ unsigned scale2bf(unsigned p, float ns) {
    const float a = __uint_as_float(p << 16) * ns;
    const float b = __uint_as_float(p & 0xffff0000u) * ns;
    return (unsigned)f2bf(a) | ((unsigned)f2bf(b) << 16);
}

// ---------------- head constant: cc = b2.Wp_a + b2.Wp_c + bp ----------------
__global__ void head_const_kernel(const float* __restrict__ b2, const float* __restrict__ Wp,
                                  const float* __restrict__ bp, float* __restrict__ consts) {
    const int l = threadIdx.x;           // 64 lanes
    const float2 bb = *(const float2*)&b2[2 * l];
    const float2 wa = *(const float2*)&Wp[2 * l];
    const float2 wc = *(const float2*)&Wp[F + 2 * l];
    float s = bb.x * (wa.x + wc.x) + bb.y * (wa.y + wc.y);
    #pragma unroll
    for (int m = 32; m > 0; m >>= 1) s += __shfl_xor(s, m);
    if (l == 0) consts[0] = s + bp[0];
}

// ---------------- V = W2 @ Wp  (fold layer-2 GEMM through the linear head) ----------------
__global__ void headw_kernel(const float* __restrict__ W2, const float* __restrict__ Wp,
                             float2* __restrict__ V) {
    const int i = threadIdx.x;           // 128 threads
    float sa = 0.f, sc = 0.f;
    #pragma unroll 8
    for (int j = 0; j < F; ++j) {
        const float w = W2[i * F + j];
        sa += w * Wp[j];
        sc += w * Wp[F + j];
    }
    V[i] = make_float2(sa, sc);
}

// ---------------- init: bucket cursors to region starts ----------------
__global__ void init_cursor_kernel(int* __restrict__ gCur) {
    const int b = blockIdx.x * blockDim.x + threadIdx.x;
    if (b < NBUCK) gCur[b] = b * BCAPG;
}

// ---------------- fused gemm1 (MFMA, B-in-registers) + binning  [R9/R11 known-good] ----------------
// blockIdx%2==1 -> fill role: LDS-staged bucket binning + deg_out atomics
// blockIdx%2==0 -> gemm role: hsQ[w][n][:] = bf16(x[n][:] @ W1) column-quartered
//   (quarter q = wave id w; slice col = nb*16+ml), UNnormalized.
__global__ __launch_bounds__(256, 3)
void gemm1_fill_kernel(const float* __restrict__ in, const float* __restrict__ W,
                       unsigned short* __restrict__ out_bf,
                       const int* __restrict__ src, const int* __restrict__ dst,
                       int* __restrict__ deg_out, int* __restrict__ gCur,
                       int* __restrict__ srcPart) {
    __shared__ __align__(16) char smem[31264];

    const int g = blockIdx.x;
    const int tid = threadIdx.x;

    if (g & 1) {                                    // ---- fill role (384 blocks)
        int* packedL = (int*)smem;                  // CHUNK ints
        unsigned short* bktL = (unsigned short*)(packedL + CHUNK);  // CHUNK u16
        int* hist = (int*)((char*)smem + 25008);    // NBUCK ints
        int* curL = hist + NBUCK;                   // NBUCK ints
        const int e0 = (g >> 1) * CHUNK;
        const int nCh = min(CHUNK, NE - e0);
        for (int i = tid; i < NBUCK; i += 256) hist[i] = 0;
        __syncthreads();
        for (int i = tid; i < nCh; i += 256) {
            const int s = src[e0 + i];
            const int d = dst[e0 + i];
            atomicAdd(&deg_out[s], 1);
            const int bkt = d >> 7;
            atomicAdd(&hist[bkt], 1);
            packedL[i] = s | ((d & 127) << 17);
            bktL[i] = (unsigned short)bkt;
        }
        __syncthreads();
        for (int b = tid; b < NBUCK; b += 256) {
            const int c = hist[b];
            curL[b] = (c > 0) ? atomicAdd(&gCur[b], c) : 0;
        }
        __syncthreads();
        for (int i = tid; i < nCh; i += 256) {
            const int bkt = bktL[i];
            const int p = atomicAdd(&curL[bkt], 1);
            if (p < (bkt + 1) * BCAPG)
                srcPart[p] = packedL[i];
        }
        return;
    }

    // ---- gemm role (384 blocks), tile = 32 rows x 128 cols
    char* A_hi = smem;                  // 8 KB
    char* A_lo = smem + 8192;           // 8 KB

    const int gid  = g >> 1;
    const int w    = tid >> 6;          // wave 0..3 -> cols 32w..32w+31 (= quarter w)
    const int lane = tid & 63;
    const int ml   = lane & 15;
    const int quad = lane >> 4;

    // preload B frags once: Bf[kb][nb], j: bf16(W[(kb*32+quad*8+j)*F + 32w+nb*16+ml])
    bf16x8 Bf[4][2];
    #pragma unroll
    for (int kb = 0; kb < 4; ++kb) {
        #pragma unroll
        for (int nb = 0; nb < 2; ++nb) {
            const int n = 32 * w + nb * 16 + ml;
            const int k0 = kb * 32 + quad * 8;
            #pragma unroll
            for (int j = 0; j < 8; ++j)
                Bf[kb][nb][j] = (short)f2bf(W[(k0 + j) * F + n]);
        }
    }

    unsigned short* outq = out_bf + (size_t)w * NN * 32;   // this wave's column slice

    const int nTiles = NN / 32;                     // 3125
    for (int tile = gid; tile < nTiles; tile += 384) {
        const int row0 = tile * 32;
        __syncthreads();
        // stage A tile in fragment order, split hi/lo: 512 chunks of 8 floats
        #pragma unroll
        for (int c = 0; c < 2; ++c) {
            const int i2 = tid + 256 * c;           // 0..511
            const int m  = i2 >> 4;                 // row 0..31
            const int o  = i2 & 15;                 // k-octet
            const float* xr = &in[(size_t)(row0 + m) * F + o * 8];
            const float4 v0 = *(const float4*)xr;
            const float4 v1 = *(const float4*)(xr + 4);
            float xv[8] = {v0.x, v0.y, v0.z, v0.w, v1.x, v1.y, v1.z, v1.w};
            short hi8[8], lo8[8];
            #pragma unroll
            for (int j = 0; j < 8; ++j) {
                const unsigned short h = f2bf(xv[j]);
                hi8[j] = (short)h;
                lo8[j] = (short)f2bf(xv[j] - __uint_as_float((unsigned)h << 16));
            }
            const int kb2 = o >> 2, q2 = o & 3, ml2 = m & 15, mh2 = m >> 4;
            const int fo = (((mh2 * 4 + kb2) * 64) + q2 * 16 + ml2) * 16;
            *(bf16x8*)(A_hi + fo) = *(bf16x8*)hi8;
            *(bf16x8*)(A_lo + fo) = *(bf16x8*)lo8;
        }
        __syncthreads();

        f32x4 acc00 = {0,0,0,0}, acc01 = {0,0,0,0}, acc10 = {0,0,0,0}, acc11 = {0,0,0,0};
        #pragma unroll
        for (int kb = 0; kb < 4; ++kb) {
            const int o0 = (kb * 64 + lane) * 16;
            const int o1 = ((4 + kb) * 64 + lane) * 16;
            const bf16x8 ah0 = *(const bf16x8*)(A_hi + o0);
            const bf16x8 ah1 = *(const bf16x8*)(A_hi + o1);
            const bf16x8 al0 = *(const bf16x8*)(A_lo + o0);
            const bf16x8 al1 = *(const bf16x8*)(A_lo + o1);
            acc00 = __builtin_amdgcn_mfma_f32_16x16x32_bf16(ah0, Bf[kb][0], acc00, 0, 0, 0);
            acc00 = __builtin_amdgcn_mfma_f32_16x16x32_bf16(al0, Bf[kb][0], acc00, 0, 0, 0);
            acc01 = __builtin_amdgcn_mfma_f32_16x16x32_bf16(ah0, Bf[kb][1], acc01, 0, 0, 0);
            acc01 = __builtin_amdgcn_mfma_f32_16x16x32_bf16(al0, Bf[kb][1], acc01, 0, 0, 0);
            acc10 = __builtin_amdgcn_mfma_f32_16x16x32_bf16(ah1, Bf[kb][0], acc10, 0, 0, 0);
            acc10 = __builtin_amdgcn_mfma_f32_16x16x32_bf16(al1, Bf[kb][0], acc10, 0, 0, 0);
            acc11 = __builtin_amdgcn_mfma_f32_16x16x32_bf16(ah1, Bf[kb][1], acc11, 0, 0, 0);
            acc11 = __builtin_amdgcn_mfma_f32_16x16x32_bf16(al1, Bf[kb][1], acc11, 0, 0, 0);
        }

        // epilogue: C/D layout col=lane&15, row=quad*4+reg; store into column slice
        #pragma unroll
        for (int mh = 0; mh < 2; ++mh) {
            #pragma unroll
            for (int nb = 0; nb < 2; ++nb) {
                const f32x4 a = (mh == 0) ? (nb == 0 ? acc00 : acc01)
                                          : (nb == 0 ? acc10 : acc11);
                const int row = row0 + mh * 16 + quad * 4;
                const int sc  = nb * 16 + ml;       // 0..31 within slice
                #pragma unroll
                for (int r = 0; r < 4; ++r)
                    outq[(size_t)(row + r) * 32 + sc] = f2bf(a[r]);
            }
        }
    }
}

__global__ void normsrc_kernel(const int* __restrict__ deg_out, float* __restrict__ norm_src, int nN) {
    const int n = blockIdx.x * blockDim.x + threadIdx.x;
    if (n < nN) norm_src[n] = rsqrtf((float)max(deg_out[n], 1));
}

// ---------------- sort (per-bucket LDS counting sort) + hs pre-scale by norm_src ----------------
// blocks [0, NBUCK)        : sort bucket -> sortedOut (plain src), offs/ends/norm_dst
// blocks [NBUCK, NBUCK+SCALEB): in-place scale hs rows by norm_src (streaming)
__global__ __launch_bounds__(256)
void sortscale_kernel(const int* __restrict__ srcPart, const int* __restrict__ gCur,
                      int* __restrict__ sortedOut, const float* __restrict__ norm_src,
                      unsigned short* __restrict__ hs,
                      int* __restrict__ offs, int* __restrict__ ends,
                      float* __restrict__ norm_dst) {
    __shared__ int cnt[128];
    __shared__ int loc[128];
    __shared__ int cur[128];
    __shared__ int sortedL[BCAPG];

    const int g = blockIdx.x;
    const int tid = threadIdx.x;

    if (g >= NBUCK) {                               // ---- scale role
        const int sb = g - NBUCK;
        uint4* hs4 = (uint4*)hs;                    // 8 bf16 per uint4
        const int total4 = NN * 16;                 // NN*128/8
        for (int i = sb * 256 + tid; i < total4; i += SCALEB * 256) {
            const int node = (i >> 2) % NN;         // 4 uint4 per 32-col row
            const float ns = norm_src[node];
            uint4 v = hs4[i];
            v.x = scale2bf(v.x, ns);
            v.y = scale2bf(v.y, ns);
            v.z = scale2bf(v.z, ns);
            v.w = scale2bf(v.w, ns);
            hs4[i] = v;
        }
        return;
    }

    // ---- sort role (one block per 128-node bucket)
    const int b   = g;
    const int nlo = b * 128;
    const int nCnt = min(128, NN - nlo);
    const int eBase = b * BCAPG;
    const int total = min(gCur[b] - eBase, BCAPG);

    if (tid < 128) cnt[tid] = 0;
    __syncthreads();
    for (int i = tid; i < total; i += 256)
        atomicAdd(&cnt[(srcPart[eBase + i] >> 17) & 127], 1);
    __syncthreads();
    if (tid < 128) loc[tid] = cnt[tid];
    __syncthreads();
    for (int off = 1; off < 128; off <<= 1) {
        int v = 0;
        if (tid < 128 && tid >= off) v = loc[tid - off];
        __syncthreads();
        if (tid < 128) loc[tid] += v;
        __syncthreads();
    }
    if (tid < 128) cur[tid] = loc[tid] - cnt[tid];
    if (tid < nCnt) {
        const int st = eBase + loc[tid] - cnt[tid];
        offs[nlo + tid] = st;
        ends[nlo + tid] = st + cnt[tid];
        norm_dst[nlo + tid] = rsqrtf((float)max(cnt[tid], 1));
    }
    __syncthreads();
    for (int i = tid; i < total; i += 256) {
        const int v = srcPart[eBase + i];
        const int r = atomicAdd(&cur[(v >> 17) & 127], 1);
        sortedL[r] = v & 0x1FFFF;
    }
    __syncthreads();
    for (int i = tid; i < total; i += 256)
        sortedOut[eBase + i] = sortedL[i];
}

// ---------------- quartered gather + per-quarter head-fold partials ----------------
// 4 phases x NBUCK blocks (phase = blockIdx/NBUCK -> dispatch-ordered so concurrent
// blocks share one 6.4 MB column slice: L2-scale working set). No LDS.
// Per node: accQ[k] = sum_e hsQ[ph][src_e][k]  (hs pre-scaled by norm_src)
// uwQ[ph][n] = norm_src[n] * Sum_k relu(accQ[k]*nd + b1[ph*32+k]) * V[ph*32+k]
__global__ __launch_bounds__(256)
void gather4_kernel(const unsigned short* __restrict__ hs, const int* __restrict__ sortedOut,
                    const int* __restrict__ offs, const int* __restrict__ ends,
                    const float* __restrict__ norm_dst, const float* __restrict__ norm_src,
                    const float* __restrict__ b1, const float2* __restrict__ V,
                    float2* __restrict__ uwQ) {
    const int blk = blockIdx.x;
    const int ph  = blk / NBUCK;
    const int b   = blk - ph * NBUCK;
    const int tid = threadIdx.x;
    const int w   = tid >> 6;
    const int l   = tid & 63;
    const int eo  = l >> 3;          // edge slot 0..7
    const int cl  = l & 7;           // col lane: cols cl*4..cl*4+3 of the slice
    const int nlo = b * 128;
    const int nCnt = min(128, NN - nlo);
    const unsigned short* hsq = hs + (size_t)ph * NN * 32;

    const int kb = ph * 32 + cl * 4;
    float bb[4];
    *(float4*)bb = *(const float4*)&b1[kb];
    float2 Vl[4];
    #pragma unroll
    for (int k = 0; k < 4; ++k) Vl[k] = V[kb + k];

    const int nhEnd = min((w + 1) * 32, nCnt);
    for (int nh = w * 32; nh < nhEnd; ++nh) {
        const int n = nlo + nh;
        const int beg = offs[n];
        const int end = ends[n];
        float acc[4] = {0.f, 0.f, 0.f, 0.f};
        int j = beg;
        for (; j + 16 <= end; j += 16) {            // 16 edges in flight per wave
            const int s0 = sortedOut[j + eo];
            const int s1 = sortedOut[j + 8 + eo];
            const uint2 v0 = *(const uint2*)&hsq[(size_t)s0 * 32 + cl * 4];
            const uint2 v1 = *(const uint2*)&hsq[(size_t)s1 * 32 + cl * 4];
            acc_bf4(v0, acc);
            acc_bf4(v1, acc);
        }
        for (; j + 8 <= end; j += 8) {
            const int s = sortedOut[j + eo];
            acc_bf4(*(const uint2*)&hsq[(size_t)s * 32 + cl * 4], acc);
        }
        if (j + eo < end) {
            const int s = sortedOut[j + eo];
            acc_bf4(*(const uint2*)&hsq[(size_t)s * 32 + cl * 4], acc);
        }
        // reduce over the 8 edge slots (lanes with same cl)
        #pragma unroll
        for (int k = 0; k < 4; ++k) {
            acc[k] += __shfl_xor(acc[k], 8);
            acc[k] += __shfl_xor(acc[k], 16);
            acc[k] += __shfl_xor(acc[k], 32);
        }
        const float nd = norm_dst[n];
        float pa = 0.f, pc = 0.f;
        #pragma unroll
        for (int k = 0; k < 4; ++k) {
            const float ok = fmaxf(acc[k] * nd + bb[k], 0.f);
            pa += ok * Vl[k].x;
            pc += ok * Vl[k].y;
        }
        #pragma unroll
        for (int m = 1; m <= 4; m <<= 1) {
            pa += __shfl_xor(pa, m);
            pc += __shfl_xor(pc, m);
        }
        if (l == 0) {
            const float ns = norm_src[n];
            uwQ[(size_t)ph * NN + n] = make_float2(ns * pa, ns * pc);
        }
    }
}

// ---------------- combine quarter partials ----------------
__global__ void combine_kernel(const float2* __restrict__ uwQ, float2* __restrict__ uw, int nN) {
    const int n = blockIdx.x * blockDim.x + threadIdx.x;
    if (n < nN) {
        const float2 a = uwQ[n];
        const float2 b = uwQ[NN + n];
        const float2 c = uwQ[2 * NN + n];
        const float2 d = uwQ[3 * NN + n];
        uw[n] = make_float2(a.x + b.x + c.x + d.x, a.y + b.y + c.y + d.y);
    }
}

// ---------------- layer-2 scalar aggregation ----------------
__global__ void ac_kernel(const float2* __restrict__ uw, const int* __restrict__ sorted_src,
                          const int* __restrict__ offs, const int* __restrict__ ends,
                          const float* __restrict__ norm_dst,
                          float* __restrict__ A, float* __restrict__ C, int nN) {
    const int n = blockIdx.x * blockDim.x + threadIdx.x;
    if (n >= nN) return;
    const int beg = offs[n];
    const int end = ends[n];
    float su = 0.f, sw = 0.f;
    int j = beg;
    for (; j + 2 <= end; j += 2) {
        const float2 t0 = uw[sorted_src[j]];
        const float2 t1 = uw[sorted_src[j + 1]];
        su += t0.x + t1.x;
        sw += t0.y + t1.y;
    }
    if (j < end) {
        const float2 t = uw[sorted_src[j]];
        su += t.x;
        sw += t.y;
    }
    const float nd = norm_dst[n];
    A[n] = nd * su;
    C[n] = nd * sw;
}

// ---------------- edge scores ----------------
__global__ void score_kernel(const float* __restrict__ A, const float* __restrict__ C,
                             const int* __restrict__ src, const int* __restrict__ dst,
                             const float* __restrict__ consts, float* __restrict__ out, int nE) {
    const int e = blockIdx.x * blockDim.x + threadIdx.x;
    if (e < nE) {
        const float z = A[src[e]] + C[dst[e]] + consts[0];
        out[e] = 1.f / (1.f + __expf(-z));
    }
}

extern "C" void kernel_launch(void* const* d_in, const int* in_sizes, int n_in,
                              void* d_out, int out_size, void* d_ws, size_t ws_size,
                              hipStream_t stream) {
    const float* x  = (const float*)d_in[0];
    const float* W1 = (const float*)d_in[1];
    const float* b1 = (const float*)d_in[2];
    const float* W2 = (const float*)d_in[3];
    const float* b2 = (const float*)d_in[4];
    const float* Wp = (const float*)d_in[5];
    const float* bp = (const float*)d_in[6];
    const int*   src = (const int*)d_in[7];
    const int*   dst = (const int*)d_in[8];
    float* out = (float*)d_out;

    float* ws        = (float*)d_ws;
    float* norm_src  = ws;                        // NPAD
    float* bufA      = ws + NPAD;                 // NPAD: deg_out(int), later A[]
    float* bufC      = ws + 2 * NPAD;             // NPAD: C[]
    float* norm_dst  = ws + 3 * NPAD;             // NPAD
    int*   offs      = (int*)(ws + 4 * NPAD);     // NPAD
    int*   ends      = offs + NPAD;               // NPAD
    int*   gCur      = ends + NPAD;               // 1024
    float* consts    = (float*)(gCur + 1024);     // 16
    float2* V        = (float2*)(consts + 16);    // 128 float2
    float2* uw       = V + 128;                   // NN float2
    float2* uwQ      = uw + NN;                   // 4*NN float2 (3.2 MB)
    int*   srcPart   = (int*)(uwQ + 4 * NN);      // NBUCK*BCAPG ints (8.0 MB)
    int*   sortedOut = srcPart + (size_t)NBUCK * BCAPG;   // NBUCK*BCAPG ints (8.0 MB)
    unsigned short* hs_bf = (unsigned short*)(sortedOut + (size_t)NBUCK * BCAPG);  // 4 x NN x 32 bf16

    // init counters + folded head weights
    hipMemsetAsync(bufA, 0, NPAD * sizeof(int), stream);        // deg_out
    init_cursor_kernel<<<4, 256, 0, stream>>>(gCur);
    head_const_kernel<<<1, 64, 0, stream>>>(b2, Wp, bp, consts);
    headw_kernel<<<1, 128, 0, stream>>>(W2, Wp, V);

    // layer-1 MFMA GEMM (quartered, unnormalized) overlapped with degree count + binning
    gemm1_fill_kernel<<<768, 256, 0, stream>>>(x, W1, hs_bf, src, dst,
                                               (int*)bufA, gCur, srcPart);

    normsrc_kernel<<<(NN + 255) / 256, 256, 0, stream>>>((const int*)bufA, norm_src, NN);

    // per-bucket sort (-> sortedOut, offs/ends/norm_dst) overlapped with hs *= norm_src
    sortscale_kernel<<<NBUCK + SCALEB, 256, 0, stream>>>(srcPart, gCur, sortedOut,
                                                         norm_src, hs_bf,
                                                         offs, ends, norm_dst);

    // quartered gather + per-quarter head fold -> uwQ
    gather4_kernel<<<NBUCK * 4, 256, 0, stream>>>(hs_bf, sortedOut, offs, ends,
                                                  norm_dst, norm_src, b1, V, uwQ);

    combine_kernel<<<(NN + 255) / 256, 256, 0, stream>>>(uwQ, uw, NN);

    // layer-2 aggregation collapsed to scalar sums
    ac_kernel<<<(NN + 255) / 256, 256, 0, stream>>>(uw, sortedOut, offs, ends, norm_dst,
                                                    bufA, bufC, NN);

    // edge scores
    score_kernel<<<(NE + 255) / 256, 256, 0, stream>>>(bufA, bufC, src, dst, consts, out, NE);
}

// Round 13
// 312.360 us; speedup vs baseline: 1.2833x; 1.2833x over previous
//
#include <hip/hip_runtime.h>
#include <cstdint>
#include <cstddef>

#define NN 100000
#define NE 1600000
#define F  128
#define NPAD 100352          // 98 * 1024
#define NBUCK 782            // ceil(NN / 128) buckets of 128 nodes
#define BCAPG 2560           // padded region capacity per bucket (mean 2046, +11 sd)
#define CHUNK 4167           // ceil(NE / 384) fill blocks

typedef __attribute__((ext_vector_type(8))) short bf16x8;
typedef __attribute__((ext_vector_type(4))) float f32x4;

// bf16 helpers (RNE)
__device__ __forceinline__ unsigned short f2bf(float f) {
    unsigned u = __float_as_uint(f);
    unsigned r = (u + 0x7fffu + ((u >> 16) & 1u)) >> 16;
    return (unsigned short)r;
}
__device__ __forceinline__ void acc_bf8s(const uint4 v, const float ns, float* acc) {
    acc[0] += __uint_as_float(v.x << 16) * ns;
    acc[1] += __uint_as_float(v.x & 0xffff0000u) * ns;
    acc[2] += __uint_as_float(v.y << 16) * ns;
    acc[3] += __uint_as_float(v.y & 0xffff0000u) * ns;
    acc[4] += __uint_as_float(v.z << 16) * ns;
    acc[5] += __uint_as_float(v.z & 0xffff0000u) * ns;
    acc[6] += __uint_as_float(v.w << 16) * ns;
    acc[7] += __uint_as_float(v.w & 0xffff0000u) * ns;
}

// ---------------- setup: bucket cursors + head constant + V = W2 @ Wp ----------------
__global__ void setup_kernel(int* __restrict__ gCur,
                             const float* __restrict__ W2, const float* __restrict__ Wp,
                             const float* __restrict__ b2, const float* __restrict__ bp,
                             float* __restrict__ consts, float2* __restrict__ V) {
    const int g = blockIdx.x;
    const int tid = threadIdx.x;
    if (g < 4) {
        const int b = g * 256 + tid;
        if (b < NBUCK) gCur[b] = b * BCAPG;
        return;
    }
    // block 4: head fold weights + constant
    if (tid < 128) {                      // V[i] = (W2[i]·Wp_a, W2[i]·Wp_c)
        float sa = 0.f, sc = 0.f;
        #pragma unroll 8
        for (int j = 0; j < F; ++j) {
            const float w = W2[tid * F + j];
            sa += w * Wp[j];
            sc += w * Wp[F + j];
        }
        V[tid] = make_float2(sa, sc);
    } else if (tid < 192) {               // wave 2: cc = b2.Wp_a + b2.Wp_c + bp
        const int l = tid - 128;
        const float2 bb = *(const float2*)&b2[2 * l];
        const float2 wa = *(const float2*)&Wp[2 * l];
        const float2 wc = *(const float2*)&Wp[F + 2 * l];
        float s = bb.x * (wa.x + wc.x) + bb.y * (wa.y + wc.y);
        #pragma unroll
        for (int m = 32; m > 0; m >>= 1) s += __shfl_xor(s, m);
        if (l == 0) consts[0] = s + bp[0];
    }
}

// ---------------- fused gemm1 (MFMA, B-in-registers) + binning ----------------
// blockIdx%2==1 -> fill role: LDS-staged bucket binning + deg_out atomics
// blockIdx%2==0 -> gemm role: hs_bf[n][:] = bf16(x[n][:] @ W1), single bf16 MFMA
//   (x rounded to bf16 once — hs storage is bf16 anyway, so precision is comparable)
__global__ __launch_bounds__(256, 3)
void gemm1_fill_kernel(const float* __restrict__ in, const float* __restrict__ W,
                       unsigned short* __restrict__ out_bf,
                       const int* __restrict__ src, const int* __restrict__ dst,
                       int* __restrict__ deg_out, int* __restrict__ gCur,
                       int* __restrict__ srcPart) {
    __shared__ __align__(16) char smem[31264];

    const int g = blockIdx.x;
    const int tid = threadIdx.x;

    if (g & 1) {                                    // ---- fill role (384 blocks)
        int* packedL = (int*)smem;                  // CHUNK ints
        unsigned short* bktL = (unsigned short*)(packedL + CHUNK);  // CHUNK u16
        int* hist = (int*)((char*)smem + 25008);    // NBUCK ints
        int* curL = hist + NBUCK;                   // NBUCK ints
        const int e0 = (g >> 1) * CHUNK;
        const int nCh = min(CHUNK, NE - e0);
        for (int i = tid; i < NBUCK; i += 256) hist[i] = 0;
        __syncthreads();
        for (int i = tid; i < nCh; i += 256) {
            const int s = src[e0 + i];
            const int d = dst[e0 + i];
            atomicAdd(&deg_out[s], 1);
            const int bkt = d >> 7;
            atomicAdd(&hist[bkt], 1);
            packedL[i] = s | ((d & 127) << 17);
            bktL[i] = (unsigned short)bkt;
        }
        __syncthreads();
        for (int b = tid; b < NBUCK; b += 256) {
            const int c = hist[b];
            curL[b] = (c > 0) ? atomicAdd(&gCur[b], c) : 0;
        }
        __syncthreads();
        for (int i = tid; i < nCh; i += 256) {
            const int bkt = bktL[i];
            const int p = atomicAdd(&curL[bkt], 1);
            if (p < (bkt + 1) * BCAPG)
                srcPart[p] = packedL[i];
        }
        return;
    }

    // ---- gemm role (384 blocks), tile = 32 rows x 128 cols
    char* A_s = smem;                   // 8 KB fragment-ordered A tile (bf16)

    const int gid  = g >> 1;
    const int w    = tid >> 6;          // wave 0..3 -> cols 32w..32w+31
    const int lane = tid & 63;
    const int ml   = lane & 15;
    const int quad = lane >> 4;

    // preload B frags once: Bf[kb][nb], j: bf16(W[(kb*32+quad*8+j)*F + 32w+nb*16+ml])
    bf16x8 Bf[4][2];
    #pragma unroll
    for (int kb = 0; kb < 4; ++kb) {
        #pragma unroll
        for (int nb = 0; nb < 2; ++nb) {
            const int n = 32 * w + nb * 16 + ml;
            const int k0 = kb * 32 + quad * 8;
            #pragma unroll
            for (int j = 0; j < 8; ++j)
                Bf[kb][nb][j] = (short)f2bf(W[(k0 + j) * F + n]);
        }
    }

    const int nTiles = NN / 32;                     // 3125
    for (int tile = gid; tile < nTiles; tile += 384) {
        const int row0 = tile * 32;
        __syncthreads();
        // stage A tile in fragment order: 512 chunks of 8 floats -> bf16
        #pragma unroll
        for (int c = 0; c < 2; ++c) {
            const int i2 = tid + 256 * c;           // 0..511
            const int m  = i2 >> 4;                 // row 0..31
            const int o  = i2 & 15;                 // k-octet
            const float* xr = &in[(size_t)(row0 + m) * F + o * 8];
            const float4 v0 = *(const float4*)xr;
            const float4 v1 = *(const float4*)(xr + 4);
            short h8[8];
            h8[0] = (short)f2bf(v0.x); h8[1] = (short)f2bf(v0.y);
            h8[2] = (short)f2bf(v0.z); h8[3] = (short)f2bf(v0.w);
            h8[4] = (short)f2bf(v1.x); h8[5] = (short)f2bf(v1.y);
            h8[6] = (short)f2bf(v1.z); h8[7] = (short)f2bf(v1.w);
            const int kb2 = o >> 2, q2 = o & 3, ml2 = m & 15, mh2 = m >> 4;
            const int fo = (((mh2 * 4 + kb2) * 64) + q2 * 16 + ml2) * 16;
            *(bf16x8*)(A_s + fo) = *(bf16x8*)h8;
        }
        __syncthreads();

        f32x4 acc00 = {0,0,0,0}, acc01 = {0,0,0,0}, acc10 = {0,0,0,0}, acc11 = {0,0,0,0};
        #pragma unroll
        for (int kb = 0; kb < 4; ++kb) {
            const bf16x8 ah0 = *(const bf16x8*)(A_s + (kb * 64 + lane) * 16);
            const bf16x8 ah1 = *(const bf16x8*)(A_s + ((4 + kb) * 64 + lane) * 16);
            acc00 = __builtin_amdgcn_mfma_f32_16x16x32_bf16(ah0, Bf[kb][0], acc00, 0, 0, 0);
            acc01 = __builtin_amdgcn_mfma_f32_16x16x32_bf16(ah0, Bf[kb][1], acc01, 0, 0, 0);
            acc10 = __builtin_amdgcn_mfma_f32_16x16x32_bf16(ah1, Bf[kb][0], acc10, 0, 0, 0);
            acc11 = __builtin_amdgcn_mfma_f32_16x16x32_bf16(ah1, Bf[kb][1], acc11, 0, 0, 0);
        }

        // epilogue: C/D layout col=lane&15, row=quad*4+reg
        #pragma unroll
        for (int mh = 0; mh < 2; ++mh) {
            #pragma unroll
            for (int nb = 0; nb < 2; ++nb) {
                const f32x4 a = (mh == 0) ? (nb == 0 ? acc00 : acc01)
                                          : (nb == 0 ? acc10 : acc11);
                const int row = row0 + mh * 16 + quad * 4;
                const int col = 32 * w + nb * 16 + ml;
                #pragma unroll
                for (int r = 0; r < 4; ++r)
                    out_bf[(size_t)(row + r) * F + col] = f2bf(a[r]);
            }
        }
    }
}

__global__ void normsrc_kernel(const int* __restrict__ deg_out, float* __restrict__ norm_src, int nN) {
    const int n = blockIdx.x * blockDim.x + threadIdx.x;
    if (n < nN) norm_src[n] = rsqrtf((float)max(deg_out[n], 1));
}

// ---------------- gather + per-bucket LDS counting sort + fused layer-2 head fold ----------------
// [R9 known-good structure]
__global__ __launch_bounds__(256)
void gather_sort_kernel(const unsigned short* __restrict__ hs,
                        int* __restrict__ srcPart, const int* __restrict__ gCur,
                        const float* __restrict__ norm_src, const float* __restrict__ bias,
                        const float2* __restrict__ V, float2* __restrict__ uw,
                        int* __restrict__ offs, int* __restrict__ ends,
                        float* __restrict__ norm_dst) {
    __shared__ int cnt[128];
    __shared__ int loc[128];       // inclusive prefix
    __shared__ int cur[128];
    __shared__ int sortedL[BCAPG];

    const int b   = blockIdx.x;
    const int tid = threadIdx.x;
    const int nlo = b * 128;
    const int nCnt = min(128, NN - nlo);
    const int eBase = b * BCAPG;
    const int total = min(gCur[b] - eBase, BCAPG);

    if (tid < 128) cnt[tid] = 0;
    __syncthreads();
    for (int i = tid; i < total; i += 256)
        atomicAdd(&cnt[(srcPart[eBase + i] >> 17) & 127], 1);
    __syncthreads();
    if (tid < 128) loc[tid] = cnt[tid];
    __syncthreads();
    for (int off = 1; off < 128; off <<= 1) {
        int v = 0;
        if (tid < 128 && tid >= off) v = loc[tid - off];
        __syncthreads();
        if (tid < 128) loc[tid] += v;
        __syncthreads();
    }
    if (tid < 128) cur[tid] = loc[tid] - cnt[tid];
    if (tid < nCnt) {
        const int st = eBase + loc[tid] - cnt[tid];
        offs[nlo + tid] = st;
        ends[nlo + tid] = st + cnt[tid];
        norm_dst[nlo + tid] = rsqrtf((float)max(cnt[tid], 1));
    }
    __syncthreads();
    for (int i = tid; i < total; i += 256) {
        const int v = srcPart[eBase + i];
        const int r = atomicAdd(&cur[(v >> 17) & 127], 1);
        sortedL[r] = v & 0x1FFFF;
    }
    __syncthreads();
    // coalesced write of sorted src ids (for ac_kernel)
    for (int i = tid; i < total; i += 256)
        srcPart[eBase + i] = sortedL[i];

    // ---- feature gather (per wave: 32 nodes; 16 lanes per edge, 8 bf16 cols/lane)
    const int w  = tid >> 6;
    const int l  = tid & 63;
    const int q  = l >> 4;
    const int c8 = (l & 15) * 8;
    float bb[8];
    *(float4*)&bb[0] = *(const float4*)&bias[c8];
    *(float4*)&bb[4] = *(const float4*)&bias[c8 + 4];
    float2 Vl[8];
    #pragma unroll
    for (int k = 0; k < 8; ++k) Vl[k] = V[c8 + k];

    const int nhEnd = min((w + 1) * 32, nCnt);
    for (int nh = w * 32; nh < nhEnd; ++nh) {
        const int end = loc[nh];
        const int beg = end - cnt[nh];
        float acc[8] = {0.f, 0.f, 0.f, 0.f, 0.f, 0.f, 0.f, 0.f};
        int j = beg;
        for (; j + 16 <= end; j += 16) {      // 16 edges in flight per wave
            const int s0 = sortedL[j + q];
            const int s1 = sortedL[j + 4 + q];
            const int s2 = sortedL[j + 8 + q];
            const int s3 = sortedL[j + 12 + q];
            const float ns0 = norm_src[s0];
            const float ns1 = norm_src[s1];
            const float ns2 = norm_src[s2];
            const float ns3 = norm_src[s3];
            const uint4 v0 = *(const uint4*)&hs[(size_t)s0 * F + c8];
            const uint4 v1 = *(const uint4*)&hs[(size_t)s1 * F + c8];
            const uint4 v2 = *(const uint4*)&hs[(size_t)s2 * F + c8];
            const uint4 v3 = *(const uint4*)&hs[(size_t)s3 * F + c8];
            acc_bf8s(v0, ns0, acc);
            acc_bf8s(v1, ns1, acc);
            acc_bf8s(v2, ns2, acc);
            acc_bf8s(v3, ns3, acc);
        }
        for (; j + 8 <= end; j += 8) {
            const int s0 = sortedL[j + q];
            const int s1 = sortedL[j + 4 + q];
            const float ns0 = norm_src[s0];
            const float ns1 = norm_src[s1];
            const uint4 v0 = *(const uint4*)&hs[(size_t)s0 * F + c8];
            const uint4 v1 = *(const uint4*)&hs[(size_t)s1 * F + c8];
            acc_bf8s(v0, ns0, acc);
            acc_bf8s(v1, ns1, acc);
        }
        for (; j + 4 <= end; j += 4) {
            const int s = sortedL[j + q];
            const float ns = norm_src[s];
            const uint4 v = *(const uint4*)&hs[(size_t)s * F + c8];
            acc_bf8s(v, ns, acc);
        }
        if (j + q < end) {
            const int s = sortedL[j + q];
            const float ns = norm_src[s];
            const uint4 v = *(const uint4*)&hs[(size_t)s * F + c8];
            acc_bf8s(v, ns, acc);
        }
        #pragma unroll
        for (int k = 0; k < 8; ++k) {
            acc[k] += __shfl_xor(acc[k], 16);
            acc[k] += __shfl_xor(acc[k], 32);
        }

        const int n = nlo + nh;
        const float nd = rsqrtf((float)max(cnt[nh], 1));
        float pa = 0.f, pc = 0.f;
        #pragma unroll
        for (int k = 0; k < 8; ++k) {
            const float ok = fmaxf(acc[k] * nd + bb[k], 0.f);
            pa += ok * Vl[k].x;
            pc += ok * Vl[k].y;
        }
        #pragma unroll
        for (int m = 1; m <= 8; m <<= 1) {
            pa += __shfl_xor(pa, m);
            pc += __shfl_xor(pc, m);
        }
        if (l == 0) {
            const float ns = norm_src[n];
            uw[n] = make_float2(ns * pa, ns * pc);
        }
    }
}

// ---------------- layer-2 scalar aggregation ----------------
__global__ void ac_kernel(const float2* __restrict__ uw, const int* __restrict__ sorted_src,
                          const int* __restrict__ offs, const int* __restrict__ ends,
                          const float* __restrict__ norm_dst,
                          float* __restrict__ A, float* __restrict__ C, int nN) {
    const int n = blockIdx.x * blockDim.x + threadIdx.x;
    if (n >= nN) return;
    const int beg = offs[n];
    const int end = ends[n];
    float su = 0.f, sw = 0.f;
    int j = beg;
    for (; j + 2 <= end; j += 2) {
        const float2 t0 = uw[sorted_src[j]];
        const float2 t1 = uw[sorted_src[j + 1]];
        su += t0.x + t1.x;
        sw += t0.y + t1.y;
    }
    if (j < end) {
        const float2 t = uw[sorted_src[j]];
        su += t.x;
        sw += t.y;
    }
    const float nd = norm_dst[n];
    A[n] = nd * su;
    C[n] = nd * sw;
}

// ---------------- edge scores (4-wide) ----------------
__global__ void score_kernel(const float* __restrict__ A, const float* __restrict__ C,
                             const int4* __restrict__ src4, const int4* __restrict__ dst4,
                             const float* __restrict__ consts, float4* __restrict__ out4,
                             int nE4) {
    const int i = blockIdx.x * blockDim.x + threadIdx.x;
    if (i < nE4) {
        const int4 s = src4[i];
        const int4 d = dst4[i];
        const float cc = consts[0];
        float4 o;
        o.x = 1.f / (1.f + __expf(-(A[s.x] + C[d.x] + cc)));
        o.y = 1.f / (1.f + __expf(-(A[s.y] + C[d.y] + cc)));
        o.z = 1.f / (1.f + __expf(-(A[s.z] + C[d.z] + cc)));
        o.w = 1.f / (1.f + __expf(-(A[s.w] + C[d.w] + cc)));
        out4[i] = o;
    }
}

extern "C" void kernel_launch(void* const* d_in, const int* in_sizes, int n_in,
                              void* d_out, int out_size, void* d_ws, size_t ws_size,
                              hipStream_t stream) {
    const float* x  = (const float*)d_in[0];
    const float* W1 = (const float*)d_in[1];
    const float* b1 = (const float*)d_in[2];
    const float* W2 = (const float*)d_in[3];
    const float* b2 = (const float*)d_in[4];
    const float* Wp = (const float*)d_in[5];
    const float* bp = (const float*)d_in[6];
    const int*   src = (const int*)d_in[7];
    const int*   dst = (const int*)d_in[8];
    float* out = (float*)d_out;

    float* ws        = (float*)d_ws;
    float* norm_src  = ws;                        // NPAD
    float* bufA      = ws + NPAD;                 // NPAD: deg_out(int), later A[]
    float* bufC      = ws + 2 * NPAD;             // NPAD: C[]
    float* norm_dst  = ws + 3 * NPAD;             // NPAD
    int*   offs      = (int*)(ws + 4 * NPAD);     // NPAD
    int*   ends      = offs + NPAD;               // NPAD
    int*   gCur      = ends + NPAD;               // 1024
    float* consts    = (float*)(gCur + 1024);     // 16
    float2* V        = (float2*)(consts + 16);    // 128 float2
    float2* uw       = V + 128;                   // NN float2
    int*   srcPart   = (int*)(uw + NN);           // NBUCK*BCAPG ints (8.0 MB)
    unsigned short* hs_bf = (unsigned short*)(srcPart + (size_t)NBUCK * BCAPG);  // NN*F bf16

    // init counters + folded head weights (one setup kernel)
    hipMemsetAsync(bufA, 0, NPAD * sizeof(int), stream);        // deg_out
    setup_kernel<<<5, 256, 0, stream>>>(gCur, W2, Wp, b2, bp, consts, V);

    // layer-1 MFMA GEMM (unnormalized) overlapped with degree count + edge binning
    gemm1_fill_kernel<<<768, 256, 0, stream>>>(x, W1, hs_bf, src, dst,
                                               (int*)bufA, gCur, srcPart);

    normsrc_kernel<<<(NN + 255) / 256, 256, 0, stream>>>((const int*)bufA, norm_src, NN);

    // per-bucket LDS sort + feature gather + folded layer-2 head -> uw, offs/ends, norm_dst
    gather_sort_kernel<<<NBUCK, 256, 0, stream>>>(hs_bf, srcPart, gCur, norm_src, b1,
                                                  V, uw, offs, ends, norm_dst);

    // layer-2 aggregation collapsed to scalar sums
    ac_kernel<<<(NN + 255) / 256, 256, 0, stream>>>(uw, srcPart, offs, ends, norm_dst,
                                                    bufA, bufC, NN);

    // edge scores (NE divisible by 4)
    score_kernel<<<(NE / 4 + 255) / 256, 256, 0, stream>>>(bufA, bufC, (const int4*)src,
                                                           (const int4*)dst, consts,
                                                           (float4*)out, NE / 4);
}